// Round 5
// baseline (2115.232 us; speedup 1.0000x reference)
//
#include <hip/hip_runtime.h>
#include <cstdint>

#define BB   128
#define SS   256
#define NDEPTH 655
#define UU   128
#define VV   512   // 4*UU
#define NPB  32

// ---------------- context features + sequence_length scalar ----------------
__global__ void context_kernel(const int* __restrict__ last_rule,
                               const int* __restrict__ move_count,
                               const int* __restrict__ node_count,
                               const int* __restrict__ problem_type,
                               float* __restrict__ out, int write_seq) {
    int i = blockIdx.x * blockDim.x + threadIdx.x;
    if (i < BB * 35) {
        int b = i / 35, c = i % 35;
        float v;
        if (c == 0)      v = (float)last_rule[b];
        else if (c == 1) v = (float)move_count[b];
        else if (c == 2) v = (float)node_count[b];
        else             v = (problem_type[b] == (c - 3)) ? 1.0f : 0.0f;
        out[i] = v;
    }
    if (write_seq && i == 0)
        out[(size_t)BB*35 + (size_t)BB*UU + (size_t)BB*SS*UU] = (float)SS;
}

// ---------------- WdWx = W_dense @ Wx  (2620 x 512), base = b_dense@Wx + b_lstm ----
__global__ void wdwx_kernel(const float* __restrict__ Wd,      // [2620,128]
                            const float* __restrict__ Wx,      // [128,512]
                            const float* __restrict__ b_dense, // [128]
                            const float* __restrict__ b_lstm,  // [512]
                            float* __restrict__ WdWx,          // [2620,512]
                            float* __restrict__ base) {        // [512]
    int v  = threadIdx.x;          // 0..511
    int k0 = blockIdx.x * 4;       // 655 blocks, 4 rows each
    const float* wd0 = Wd + (size_t)k0 * UU;   // block-uniform -> scalar loads
    float a0 = 0.f, a1 = 0.f, a2 = 0.f, a3 = 0.f;
    for (int u = 0; u < UU; ++u) {
        float wx = Wx[u * VV + v];             // coalesced, L2-resident
        a0 = fmaf(wd0[u],        wx, a0);
        a1 = fmaf(wd0[UU + u],   wx, a1);
        a2 = fmaf(wd0[2*UU + u], wx, a2);
        a3 = fmaf(wd0[3*UU + u], wx, a3);
    }
    WdWx[(size_t)(k0+0)*VV + v] = a0;
    WdWx[(size_t)(k0+1)*VV + v] = a1;
    WdWx[(size_t)(k0+2)*VV + v] = a2;
    WdWx[(size_t)(k0+3)*VV + v] = a3;
    if (blockIdx.x == 0) {
        float a = 0.f;
        for (int u = 0; u < UU; ++u) a = fmaf(b_dense[u], Wx[u * VV + v], a);
        base[v] = a + b_lstm[v];
    }
}

// ---------------- persistent per-batch LSTM, quad-gate layout --------------
// lane l of wave w: unit u = w*16 + (l>>2), gate = l&3  (keras order i,f,g,o).
// Each thread: full 128-dot for its (u,gate) column; gates meet via quad DPP
// shuffles; cell update computed redundantly per quad. One barrier per step.
__global__ __launch_bounds__(512, 2)
void lstm_kernel(const int* __restrict__ bwd,  const int* __restrict__ fwd,
                 const int* __restrict__ lbwd, const int* __restrict__ lfwd,
                 const float* __restrict__ WdWx,   // [2620,512]
                 const float* __restrict__ base,   // [512]
                 const float* __restrict__ Wh,     // [128,512]
                 float* __restrict__ hidden_states, // [B,S,U]
                 float* __restrict__ lstm_vectors) {// [B,U]
    const int b    = blockIdx.x;
    const int t    = threadIdx.x;     // 0..511
    const int lane = t & 63;
    const int w    = t >> 6;          // wave 0..7
    const int gate = lane & 3;
    const int u    = w * 16 + (lane >> 2);   // unit 0..127
    const int col  = gate * UU + u;          // column in [512]

    __shared__ __align__(16) float h_buf[2][UU];
    __shared__ int idx_lds[SS][4];

    // recurrent weight column -> registers (must stay resident: the partial
    // unroll below bounds ds_read temps so the allocator can afford wh[128])
    float wh[UU];
    #pragma unroll 8
    for (int k = 0; k < UU; ++k) wh[k] = Wh[k * VV + col];

    for (int s = t; s < SS; s += 512) {
        idx_lds[s][0] =            bwd [b*SS + s];
        idx_lds[s][1] =   NDEPTH + fwd [b*SS + s];
        idx_lds[s][2] = 2*NDEPTH + lbwd[b*SS + s];
        idx_lds[s][3] = 3*NDEPTH + lfwd[b*SS + s];
    }
    if (t < UU) h_buf[0][t] = 0.0f;
    float c    = 0.0f;                 // cell state, replicated per quad
    float bias = base[col];
    __syncthreads();

    // prefetch step-0 gather (4 coalesced rows of L2/L3-resident WdWx)
    float g0 = WdWx[(size_t)idx_lds[0][0] * VV + col];
    float g1 = WdWx[(size_t)idx_lds[0][1] * VV + col];
    float g2 = WdWx[(size_t)idx_lds[0][2] * VV + col];
    float g3 = WdWx[(size_t)idx_lds[0][3] * VV + col];

    int p = 0;
    for (int s = 0; s < SS; ++s) {
        float z = bias + (g0 + g1) + (g2 + g3);
        if (s + 1 < SS) {              // prefetch next step under the dot
            g0 = WdWx[(size_t)idx_lds[s+1][0] * VV + col];
            g1 = WdWx[(size_t)idx_lds[s+1][1] * VV + col];
            g2 = WdWx[(size_t)idx_lds[s+1][2] * VV + col];
            g3 = WdWx[(size_t)idx_lds[s+1][3] * VV + col];
        }

        // z += h . Wh[:,col] — broadcast LDS reads, bounded unroll (reg pressure)
        const float* hb = h_buf[p];
        float z0 = 0.f, z1 = 0.f, z2 = 0.f, z3 = 0.f;
        #pragma unroll 4
        for (int k = 0; k < UU; k += 4) {
            float4 hv = *(const float4*)(hb + k);   // same-addr broadcast
            z0 = fmaf(hv.x, wh[k],   z0);
            z1 = fmaf(hv.y, wh[k+1], z1);
            z2 = fmaf(hv.z, wh[k+2], z2);
            z3 = fmaf(hv.w, wh[k+3], z3);
        }
        z += (z0 + z1) + (z2 + z3);

        // activation: sigmoid; gate 2 (g) = tanh via 2*sigm(2z)-1
        float xs = (gate == 2) ? 2.0f * z : z;
        float sg = __fdividef(1.0f, 1.0f + __expf(-xs));
        float a  = (gate == 2) ? 2.0f * sg - 1.0f : sg;

        // quad exchange: v1 = act(gate^1), v2 = act(gate^2), v3 = act(gate^3)
        float v1 = __shfl_xor(a, 1);
        float v2 = __shfl_xor(a, 2);
        float v3 = __shfl_xor(v1, 2);
        float ig = (gate & 1) ? v1 * v3 : a * v2;                       // i*g
        float gf = (gate & 1) ? ((gate & 2) ? v2 : a)
                              : ((gate & 2) ? v3 : v1);                 // f
        float go = (gate & 1) ? ((gate & 2) ? a  : v2)
                              : ((gate & 2) ? v1 : v3);                 // o
        c = fmaf(gf, c, ig);
        float e  = __expf(2.0f * c);
        float tc = 1.0f - __fdividef(2.0f, e + 1.0f);                   // tanh(c)
        float h  = go * tc;

        if (gate == 0) {
            h_buf[p ^ 1][u] = h;
            hidden_states[((size_t)b * SS + s) * UU + u] = h;
        }
        __syncthreads();               // single barrier: h ready, WAR safe
        p ^= 1;
    }
    if (t < UU) lstm_vectors[(size_t)b * UU + t] = h_buf[p][t];
}

// ---------------------------------------------------------------------------
extern "C" void kernel_launch(void* const* d_in, const int* in_sizes, int n_in,
                              void* d_out, int out_size, void* d_ws, size_t ws_size,
                              hipStream_t stream) {
    const int* move_count   = (const int*)d_in[0];
    // d_in[1] moves_remaining: unused by the reference
    const int* last_rule    = (const int*)d_in[2];
    const int* node_count   = (const int*)d_in[3];
    const int* problem_type = (const int*)d_in[4];
    const int* bwd          = (const int*)d_in[5];
    const int* fwd          = (const int*)d_in[6];
    const int* lbwd         = (const int*)d_in[7];
    const int* lfwd         = (const int*)d_in[8];
    const float* Wd         = (const float*)d_in[9];
    const float* b_dense    = (const float*)d_in[10];
    const float* Wx         = (const float*)d_in[11];
    const float* Wh         = (const float*)d_in[12];
    const float* b_lstm     = (const float*)d_in[13];

    float* out  = (float*)d_out;
    float* WdWx = (float*)d_ws;                        // 2620*512*4 = 5.37 MB
    float* base = WdWx + (size_t)(4 * NDEPTH) * VV;    // +512 floats

    float* lstm_out = out + BB * 35;
    float* hs_out   = lstm_out + BB * UU;
    int write_seq = (out_size > BB*35 + BB*UU + BB*SS*UU) ? 1 : 0;

    context_kernel<<<(BB*35 + 255)/256, 256, 0, stream>>>(
        last_rule, move_count, node_count, problem_type, out, write_seq);
    wdwx_kernel<<<NDEPTH, VV, 0, stream>>>(Wd, Wx, b_dense, b_lstm, WdWx, base);
    lstm_kernel<<<BB, 512, 0, stream>>>(bwd, fwd, lbwd, lfwd, WdWx, base, Wh,
                                        hs_out, lstm_out);
}

// Round 6
// 366.236 us; speedup vs baseline: 5.7756x; 5.7756x over previous
//
#include <hip/hip_runtime.h>
#include <cstdint>

#define BB   128
#define SS   256
#define NDEPTH 655
#define UU   128
#define VV   512   // 4*UU
#define NPB  32

// ---------------- context features + sequence_length scalar ----------------
__global__ void context_kernel(const int* __restrict__ last_rule,
                               const int* __restrict__ move_count,
                               const int* __restrict__ node_count,
                               const int* __restrict__ problem_type,
                               float* __restrict__ out, int write_seq) {
    int i = blockIdx.x * blockDim.x + threadIdx.x;
    if (i < BB * 35) {
        int b = i / 35, c = i % 35;
        float v;
        if (c == 0)      v = (float)last_rule[b];
        else if (c == 1) v = (float)move_count[b];
        else if (c == 2) v = (float)node_count[b];
        else             v = (problem_type[b] == (c - 3)) ? 1.0f : 0.0f;
        out[i] = v;
    }
    if (write_seq && i == 0)
        out[(size_t)BB*35 + (size_t)BB*UU + (size_t)BB*SS*UU] = (float)SS;
}

// ---------------- WdWx = W_dense @ Wx  (2620 x 512), base = b_dense@Wx + b_lstm ----
__global__ void wdwx_kernel(const float* __restrict__ Wd,      // [2620,128]
                            const float* __restrict__ Wx,      // [128,512]
                            const float* __restrict__ b_dense, // [128]
                            const float* __restrict__ b_lstm,  // [512]
                            float* __restrict__ WdWx,          // [2620,512]
                            float* __restrict__ base) {        // [512]
    int v  = threadIdx.x;          // 0..511
    int k0 = blockIdx.x * 4;       // 655 blocks, 4 rows each
    const float* wd0 = Wd + (size_t)k0 * UU;   // block-uniform -> scalar loads
    float a0 = 0.f, a1 = 0.f, a2 = 0.f, a3 = 0.f;
    for (int u = 0; u < UU; ++u) {
        float wx = Wx[u * VV + v];             // coalesced, L2-resident
        a0 = fmaf(wd0[u],        wx, a0);
        a1 = fmaf(wd0[UU + u],   wx, a1);
        a2 = fmaf(wd0[2*UU + u], wx, a2);
        a3 = fmaf(wd0[3*UU + u], wx, a3);
    }
    WdWx[(size_t)(k0+0)*VV + v] = a0;
    WdWx[(size_t)(k0+1)*VV + v] = a1;
    WdWx[(size_t)(k0+2)*VV + v] = a2;
    WdWx[(size_t)(k0+3)*VV + v] = a3;
    if (blockIdx.x == 0) {
        float a = 0.f;
        for (int u = 0; u < UU; ++u) a = fmaf(b_dense[u], Wx[u * VV + v], a);
        base[v] = a + b_lstm[v];
    }
}

// ---------------- persistent per-batch LSTM, quad-gate layout --------------
// lane l of wave w: unit u = w*16 + (l>>2), gate = l&3  (keras order i,f,g,o).
// Full 128-dot per thread; gates meet via 3 quad shuffles; cell update
// replicated per quad. One barrier per step.
// NOTE (rule #20 / R5 post-mortem): wh[] MUST be indexed with compile-time
// constants only — full unroll — or the allocator dumps it to scratch
// (R5: VGPR=32, FETCH 2.1 GB, 8x slowdown). R2 proved full unroll stays
// in the unified VGPR/AGPR file (VGPR=100, FETCH 47 MB).
__global__ __launch_bounds__(512, 2)
void lstm_kernel(const int* __restrict__ bwd,  const int* __restrict__ fwd,
                 const int* __restrict__ lbwd, const int* __restrict__ lfwd,
                 const float* __restrict__ WdWx,   // [2620,512]
                 const float* __restrict__ base,   // [512]
                 const float* __restrict__ Wh,     // [128,512]
                 float* __restrict__ hidden_states, // [B,S,U]
                 float* __restrict__ lstm_vectors) {// [B,U]
    const int b    = blockIdx.x;
    const int t    = threadIdx.x;     // 0..511
    const int lane = t & 63;
    const int w    = t >> 6;          // wave 0..7
    const int gate = lane & 3;
    const int u    = w * 16 + (lane >> 2);   // unit 0..127
    const int col  = gate * UU + u;          // column in [512]

    __shared__ __align__(16) float h_buf[2][UU];
    __shared__ int idx_lds[SS][4];

    // recurrent weight column -> registers; FULL unroll (static indices)
    float wh[UU];
    #pragma unroll
    for (int k = 0; k < UU; ++k) wh[k] = Wh[k * VV + col];

    for (int s = t; s < SS; s += 512) {
        idx_lds[s][0] =            bwd [b*SS + s];
        idx_lds[s][1] =   NDEPTH + fwd [b*SS + s];
        idx_lds[s][2] = 2*NDEPTH + lbwd[b*SS + s];
        idx_lds[s][3] = 3*NDEPTH + lfwd[b*SS + s];
    }
    if (t < UU) h_buf[0][t] = 0.0f;
    float c    = 0.0f;                 // cell state, replicated per quad
    float bias = base[col];
    __syncthreads();

    // prefetch step-0 gather (4 coalesced rows of L2/L3-resident WdWx)
    float g0 = WdWx[(size_t)idx_lds[0][0] * VV + col];
    float g1 = WdWx[(size_t)idx_lds[0][1] * VV + col];
    float g2 = WdWx[(size_t)idx_lds[0][2] * VV + col];
    float g3 = WdWx[(size_t)idx_lds[0][3] * VV + col];

    int p = 0;
    for (int s = 0; s < SS; ++s) {
        float z = bias + (g0 + g1) + (g2 + g3);
        if (s + 1 < SS) {              // prefetch next step under the dot
            g0 = WdWx[(size_t)idx_lds[s+1][0] * VV + col];
            g1 = WdWx[(size_t)idx_lds[s+1][1] * VV + col];
            g2 = WdWx[(size_t)idx_lds[s+1][2] * VV + col];
            g3 = WdWx[(size_t)idx_lds[s+1][3] * VV + col];
        }

        // z += h . Wh[:,col] — same-address broadcast LDS reads, FULL unroll
        const float* hb = h_buf[p];
        float z0 = 0.f, z1 = 0.f, z2 = 0.f, z3 = 0.f;
        #pragma unroll
        for (int k = 0; k < UU; k += 4) {
            float4 hv = *(const float4*)(hb + k);
            z0 = fmaf(hv.x, wh[k],   z0);
            z1 = fmaf(hv.y, wh[k+1], z1);
            z2 = fmaf(hv.z, wh[k+2], z2);
            z3 = fmaf(hv.w, wh[k+3], z3);
        }
        z += (z0 + z1) + (z2 + z3);

        // activation: sigmoid; gate 2 (g) = tanh via 2*sigm(2z)-1
        float xs = (gate == 2) ? 2.0f * z : z;
        float sg = __fdividef(1.0f, 1.0f + __expf(-xs));
        float a  = (gate == 2) ? 2.0f * sg - 1.0f : sg;

        // quad exchange: v1 = act(gate^1), v2 = act(gate^2), v3 = act(gate^3)
        float v1 = __shfl_xor(a, 1);
        float v2 = __shfl_xor(a, 2);
        float v3 = __shfl_xor(v1, 2);
        float ig = (gate & 1) ? v1 * v3 : a * v2;                       // i*g
        float gf = (gate & 1) ? ((gate & 2) ? v2 : a)
                              : ((gate & 2) ? v3 : v1);                 // f
        float go = (gate & 1) ? ((gate & 2) ? a  : v2)
                              : ((gate & 2) ? v1 : v3);                 // o
        c = fmaf(gf, c, ig);
        float e  = __expf(2.0f * c);
        float tc = 1.0f - __fdividef(2.0f, e + 1.0f);                   // tanh(c)
        float h  = go * tc;

        if (gate == 0) {
            h_buf[p ^ 1][u] = h;
            hidden_states[((size_t)b * SS + s) * UU + u] = h;
        }
        __syncthreads();               // single barrier: h ready, WAR safe
        p ^= 1;
    }
    if (t < UU) lstm_vectors[(size_t)b * UU + t] = h_buf[p][t];
}

// ---------------------------------------------------------------------------
extern "C" void kernel_launch(void* const* d_in, const int* in_sizes, int n_in,
                              void* d_out, int out_size, void* d_ws, size_t ws_size,
                              hipStream_t stream) {
    const int* move_count   = (const int*)d_in[0];
    // d_in[1] moves_remaining: unused by the reference
    const int* last_rule    = (const int*)d_in[2];
    const int* node_count   = (const int*)d_in[3];
    const int* problem_type = (const int*)d_in[4];
    const int* bwd          = (const int*)d_in[5];
    const int* fwd          = (const int*)d_in[6];
    const int* lbwd         = (const int*)d_in[7];
    const int* lfwd         = (const int*)d_in[8];
    const float* Wd         = (const float*)d_in[9];
    const float* b_dense    = (const float*)d_in[10];
    const float* Wx         = (const float*)d_in[11];
    const float* Wh         = (const float*)d_in[12];
    const float* b_lstm     = (const float*)d_in[13];

    float* out  = (float*)d_out;
    float* WdWx = (float*)d_ws;                        // 2620*512*4 = 5.37 MB
    float* base = WdWx + (size_t)(4 * NDEPTH) * VV;    // +512 floats

    float* lstm_out = out + BB * 35;
    float* hs_out   = lstm_out + BB * UU;
    int write_seq = (out_size > BB*35 + BB*UU + BB*SS*UU) ? 1 : 0;

    context_kernel<<<(BB*35 + 255)/256, 256, 0, stream>>>(
        last_rule, move_count, node_count, problem_type, out, write_seq);
    wdwx_kernel<<<NDEPTH, VV, 0, stream>>>(Wd, Wx, b_dense, b_lstm, WdWx, base);
    lstm_kernel<<<BB, 512, 0, stream>>>(bwd, fwd, lbwd, lfwd, WdWx, base, Wh,
                                        hs_out, lstm_out);
}

// Round 8
// 312.583 us; speedup vs baseline: 6.7669x; 1.1716x over previous
//
#include <hip/hip_runtime.h>
#include <cstdint>

#define BB   128
#define SS   256
#define NDEPTH 655
#define UU   128
#define VV   512   // 4*UU
#define NPB  32

// ---------------- context features + sequence_length scalar ----------------
__global__ void context_kernel(const int* __restrict__ last_rule,
                               const int* __restrict__ move_count,
                               const int* __restrict__ node_count,
                               const int* __restrict__ problem_type,
                               float* __restrict__ out, int write_seq) {
    int i = blockIdx.x * blockDim.x + threadIdx.x;
    if (i < BB * 35) {
        int b = i / 35, c = i % 35;
        float v;
        if (c == 0)      v = (float)last_rule[b];
        else if (c == 1) v = (float)move_count[b];
        else if (c == 2) v = (float)node_count[b];
        else             v = (problem_type[b] == (c - 3)) ? 1.0f : 0.0f;
        out[i] = v;
    }
    if (write_seq && i == 0)
        out[(size_t)BB*35 + (size_t)BB*UU + (size_t)BB*SS*UU] = (float)SS;
}

// ---------------- WdWx = W_dense @ Wx  (2620 x 512), base = b_dense@Wx + b_lstm ----
__global__ void wdwx_kernel(const float* __restrict__ Wd,      // [2620,128]
                            const float* __restrict__ Wx,      // [128,512]
                            const float* __restrict__ b_dense, // [128]
                            const float* __restrict__ b_lstm,  // [512]
                            float* __restrict__ WdWx,          // [2620,512]
                            float* __restrict__ base) {        // [512]
    int v  = threadIdx.x;          // 0..511
    int k0 = blockIdx.x * 4;       // 655 blocks, 4 rows each
    const float* wd0 = Wd + (size_t)k0 * UU;   // block-uniform -> scalar loads
    float a0 = 0.f, a1 = 0.f, a2 = 0.f, a3 = 0.f;
    for (int u = 0; u < UU; ++u) {
        float wx = Wx[u * VV + v];             // coalesced, L2-resident
        a0 = fmaf(wd0[u],        wx, a0);
        a1 = fmaf(wd0[UU + u],   wx, a1);
        a2 = fmaf(wd0[2*UU + u], wx, a2);
        a3 = fmaf(wd0[3*UU + u], wx, a3);
    }
    WdWx[(size_t)(k0+0)*VV + v] = a0;
    WdWx[(size_t)(k0+1)*VV + v] = a1;
    WdWx[(size_t)(k0+2)*VV + v] = a2;
    WdWx[(size_t)(k0+3)*VV + v] = a3;
    if (blockIdx.x == 0) {
        float a = 0.f;
        for (int u = 0; u < UU; ++u) a = fmaf(b_dense[u], Wx[u * VV + v], a);
        base[v] = a + b_lstm[v];
    }
}

// ---------------- persistent per-batch LSTM, quad-gate + quad-split-K -----
// lane l of wave w: unit u = w*16 + (l>>2), q = l&3.
// Thread q reads ONLY h-chunk [32q..32q+32) (8 b128, bank-staggered stride-36
// layout -> 4 quad-chunks hit disjoint banks) and computes partial dots for
// ALL 4 gate columns of its unit (wh[k][gate], 128 FMAs, static indices).
// 2-stage quad butterfly (shfl_xor 1,2) -> thread q holds full dot for
// gate q. Gate algebra as validated in R5/R6. One barrier per step.
// LDS return traffic: 64 KB/step/CU (was 256 KB) -> below FMA issue floor.
__global__ __launch_bounds__(512, 2)
void lstm_kernel(const int* __restrict__ bwd,  const int* __restrict__ fwd,
                 const int* __restrict__ lbwd, const int* __restrict__ lfwd,
                 const float* __restrict__ WdWx,   // [2620,512]
                 const float* __restrict__ base,   // [512]
                 const float* __restrict__ Wh,     // [128,512]
                 float* __restrict__ hidden_states, // [B,S,U]
                 float* __restrict__ lstm_vectors) {// [B,U]
    const int b    = blockIdx.x;
    const int t    = threadIdx.x;     // 0..511
    const int lane = t & 63;
    const int w    = t >> 6;          // wave 0..7
    const int q    = lane & 3;        // gate lane (keras i,f,g,o)
    const int u    = w * 16 + (lane >> 2);   // unit 0..127
    const int col  = q * UU + u;             // this thread's gate column

    // h chunks: chunk j at float offset 36*j (banks 4j..4j+3 for b128 reads)
    __shared__ __align__(16) float h_buf[2][144];
    __shared__ int idx_lds[SS][4];

    // wh[kk*4+g] = Wh[32q+kk][g*128+u] — FULL static unroll (rule #20:
    // any runtime index -> scratch, R5: 8x slowdown)
    float wh[128];
    #pragma unroll
    for (int kk = 0; kk < 32; ++kk) {
        #pragma unroll
        for (int g = 0; g < 4; ++g)
            wh[kk*4+g] = Wh[(size_t)(32*q + kk) * VV + g*UU + u];
    }

    for (int s = t; s < SS; s += 512) {
        idx_lds[s][0] =            bwd [b*SS + s];
        idx_lds[s][1] =   NDEPTH + fwd [b*SS + s];
        idx_lds[s][2] = 2*NDEPTH + lbwd[b*SS + s];
        idx_lds[s][3] = 3*NDEPTH + lfwd[b*SS + s];
    }
    if (t < UU) h_buf[0][36*(t>>5) + (t&31)] = 0.0f;
    float c    = 0.0f;                 // cell state, replicated per quad
    float bias = base[col];
    __syncthreads();

    // prefetch step-0 gather
    float g0 = WdWx[(size_t)idx_lds[0][0] * VV + col];
    float g1 = WdWx[(size_t)idx_lds[0][1] * VV + col];
    float g2 = WdWx[(size_t)idx_lds[0][2] * VV + col];
    float g3 = WdWx[(size_t)idx_lds[0][3] * VV + col];

    const bool b0 = (q & 1) != 0;
    const bool b1 = (q & 2) != 0;

    int p = 0;
    for (int s = 0; s < SS; ++s) {
        float z = bias + (g0 + g1) + (g2 + g3);
        if (s + 1 < SS) {              // prefetch next step under the dot
            g0 = WdWx[(size_t)idx_lds[s+1][0] * VV + col];
            g1 = WdWx[(size_t)idx_lds[s+1][1] * VV + col];
            g2 = WdWx[(size_t)idx_lds[s+1][2] * VV + col];
            g3 = WdWx[(size_t)idx_lds[s+1][3] * VV + col];
        }

        // partial dots over my 32-chunk for all 4 gates of unit u
        const float* hb = h_buf[p] + 36 * q;
        float pp0 = 0.f, pp1 = 0.f, pp2 = 0.f, pp3 = 0.f;
        #pragma unroll
        for (int kk = 0; kk < 32; kk += 4) {
            float4 hv = *(const float4*)(hb + kk);
            pp0 = fmaf(hv.x, wh[(kk+0)*4+0], pp0);
            pp1 = fmaf(hv.x, wh[(kk+0)*4+1], pp1);
            pp2 = fmaf(hv.x, wh[(kk+0)*4+2], pp2);
            pp3 = fmaf(hv.x, wh[(kk+0)*4+3], pp3);
            pp0 = fmaf(hv.y, wh[(kk+1)*4+0], pp0);
            pp1 = fmaf(hv.y, wh[(kk+1)*4+1], pp1);
            pp2 = fmaf(hv.y, wh[(kk+1)*4+2], pp2);
            pp3 = fmaf(hv.y, wh[(kk+1)*4+3], pp3);
            pp0 = fmaf(hv.z, wh[(kk+2)*4+0], pp0);
            pp1 = fmaf(hv.z, wh[(kk+2)*4+1], pp1);
            pp2 = fmaf(hv.z, wh[(kk+2)*4+2], pp2);
            pp3 = fmaf(hv.z, wh[(kk+2)*4+3], pp3);
            pp0 = fmaf(hv.w, wh[(kk+3)*4+0], pp0);
            pp1 = fmaf(hv.w, wh[(kk+3)*4+1], pp1);
            pp2 = fmaf(hv.w, wh[(kk+3)*4+2], pp2);
            pp3 = fmaf(hv.w, wh[(kk+3)*4+3], pp3);
        }

        // quad transpose-reduce: thread q <- sum_q' partial[gate q]
        float keepA = b0 ? pp1 : pp0;          // gate b0
        float keepB = b0 ? pp3 : pp2;          // gate b0+2
        float sendA = b0 ? pp0 : pp1;
        float sendB = b0 ? pp2 : pp3;
        float sA = keepA + __shfl_xor(sendA, 1);
        float sB = keepB + __shfl_xor(sendB, 1);
        float send2 = b1 ? sA : sB;
        z += (b1 ? sB : sA) + __shfl_xor(send2, 2);

        // activation: sigmoid; gate 2 (g) = tanh via 2*sigm(2z)-1
        float xs = (q == 2) ? 2.0f * z : z;
        float sg = __fdividef(1.0f, 1.0f + __expf(-xs));
        float a  = (q == 2) ? 2.0f * sg - 1.0f : sg;

        // quad exchange: v1 = act(q^1), v2 = act(q^2), v3 = act(q^3)
        float v1 = __shfl_xor(a, 1);
        float v2 = __shfl_xor(a, 2);
        float v3 = __shfl_xor(v1, 2);
        float ig = (q & 1) ? v1 * v3 : a * v2;                    // i*g
        float gf = (q & 1) ? ((q & 2) ? v2 : a)
                           : ((q & 2) ? v3 : v1);                 // f
        float go = (q & 1) ? ((q & 2) ? a  : v2)
                           : ((q & 2) ? v1 : v3);                 // o
        c = fmaf(gf, c, ig);
        float e  = __expf(2.0f * c);
        float tc = 1.0f - __fdividef(2.0f, e + 1.0f);             // tanh(c)
        float h  = go * tc;

        if (q == 0) {
            h_buf[p ^ 1][36*(u>>5) + (u&31)] = h;
            hidden_states[((size_t)b * SS + s) * UU + u] = h;
        }
        __syncthreads();               // single barrier: h ready, WAR safe
        p ^= 1;
    }
    if (t < UU) lstm_vectors[(size_t)b * UU + t] = h_buf[p][36*(t>>5) + (t&31)];
}

// ---------------------------------------------------------------------------
extern "C" void kernel_launch(void* const* d_in, const int* in_sizes, int n_in,
                              void* d_out, int out_size, void* d_ws, size_t ws_size,
                              hipStream_t stream) {
    const int* move_count   = (const int*)d_in[0];
    // d_in[1] moves_remaining: unused by the reference
    const int* last_rule    = (const int*)d_in[2];
    const int* node_count   = (const int*)d_in[3];
    const int* problem_type = (const int*)d_in[4];
    const int* bwd          = (const int*)d_in[5];
    const int* fwd          = (const int*)d_in[6];
    const int* lbwd         = (const int*)d_in[7];
    const int* lfwd         = (const int*)d_in[8];
    const float* Wd         = (const float*)d_in[9];
    const float* b_dense    = (const float*)d_in[10];
    const float* Wx         = (const float*)d_in[11];
    const float* Wh         = (const float*)d_in[12];
    const float* b_lstm     = (const float*)d_in[13];

    float* out  = (float*)d_out;
    float* WdWx = (float*)d_ws;                        // 2620*512*4 = 5.37 MB
    float* base = WdWx + (size_t)(4 * NDEPTH) * VV;    // +512 floats

    float* lstm_out = out + BB * 35;
    float* hs_out   = lstm_out + BB * UU;
    int write_seq = (out_size > BB*35 + BB*UU + BB*SS*UU) ? 1 : 0;

    context_kernel<<<(BB*35 + 255)/256, 256, 0, stream>>>(
        last_rule, move_count, node_count, problem_type, out, write_seq);
    wdwx_kernel<<<NDEPTH, VV, 0, stream>>>(Wd, Wx, b_dense, b_lstm, WdWx, base);
    lstm_kernel<<<BB, 512, 0, stream>>>(bwd, fwd, lbwd, lfwd, WdWx, base, Wh,
                                        hs_out, lstm_out);
}